// Round 20
// baseline (2483.667 us; speedup 1.0000x reference)
//
#include <hip/hip_runtime.h>

#define NN 8192
#define DD 64
#define CC 128
#define XCLAMP 7.99881172180175781f
#define BUFSZ (32 * 132 + 32 * 144)   // one staging buffer: 8832 floats

// Optimization barrier: blocks FMA contraction (verified necessary).
__device__ __forceinline__ float guard(float v) {
    asm volatile("" : "+v"(v));
    return v;
}

// ---- EXACT replica of XLA EmitFastTanh f32, with_fma = true (VERIFIED) ----
// Odd bit-exactly: clamp symmetric, p = xc*even(x2), q even, IEEE div.
__device__ __forceinline__ float xla_tanhf(float x) {
    float xc = fminf(fmaxf(x, -XCLAMP), XCLAMP);
    float x2 = xc * xc;
    float p = fmaf(x2, -2.76076847742355e-16f, 2.00018790482477e-13f);
    p = fmaf(x2, p, -8.60467152213735e-11f);
    p = fmaf(x2, p, 5.12229709037114e-08f);
    p = fmaf(x2, p, 1.48572235717979e-05f);
    p = fmaf(x2, p, 6.37261928875436e-04f);
    p = fmaf(x2, p, 4.89352455891786e-03f);
    p = xc * p;
    float q = fmaf(x2, 1.19825839466702e-06f, 1.18534705686654e-04f);
    q = fmaf(x2, q, 2.26843463243900e-03f);
    q = fmaf(x2, q, 4.89352518554385e-03f);
    float r = p / q;
    return (fabsf(x) < 0.0004f) ? x : r;
}

// score = fl(max(tanh(fl(3a)),0) + fl(0.01*nz)), no contraction (VERIFIED)
__device__ __forceinline__ float score_of(float a, float nz) {
    float adj = fmaxf(xla_tanhf(3.0f * a), 0.0f);
    float m = guard(0.01f * nz);
    return adj + m;
}

// ---------------------------------------------------------------- K1 (VERIFIED)
// Nodevecs TRANSPOSED: Wt[c][n], rows 0-63 = nv1 dims, 64-127 = nv2 dims.
__global__ __launch_bounds__(256) void k1_nodevec(
    const int* __restrict__ idx,
    const float* __restrict__ emb1, const float* __restrict__ emb2,
    const float* __restrict__ w1, const float* __restrict__ b1,
    const float* __restrict__ w2, const float* __restrict__ b2,
    float* __restrict__ Wt)
{
    __shared__ float sw1[64 * 65], sw2[64 * 65];
    __shared__ float sb1[64], sb2[64];
    __shared__ float se1[4][64], se2[4][64];
    int t = threadIdx.x;
    for (int i = t; i < 4096; i += 256) {
        int r = i >> 6, c = i & 63;
        sw1[r * 65 + c] = w1[i];
        sw2[r * 65 + c] = w2[i];
    }
    if (t < 64) { sb1[t] = b1[t]; sb2[t] = b2[t]; }
    int nl = t >> 6, d = t & 63;
    int n = blockIdx.x * 4 + nl;
    bool is64 = (idx[1] == 0);
    int g = (is64 ? idx[2 * n] : idx[n]) & 8191;
    se1[nl][d] = emb1[g * 64 + d];
    se2[nl][d] = emb2[g * 64 + d];
    __syncthreads();
    float z1 = 0.0f, z2 = 0.0f;
#pragma unroll 16
    for (int q = 0; q < 64; ++q) {
        z1 = fmaf(se1[nl][q], sw1[d * 65 + q], z1);
        z2 = fmaf(se2[nl][q], sw2[d * 65 + q], z2);
    }
    z1 = 3.0f * guard(z1 + sb1[d]);
    z2 = 3.0f * guard(z2 + sb2[d]);
    Wt[(size_t)d * NN + n]        = xla_tanhf(z1);
    Wt[(size_t)(64 + d) * NN + n] = xla_tanhf(z2);
}

// ---------------------------------------------------------------- K_INIT
__global__ __launch_bounds__(256) void k_init(
    float* __restrict__ listVal, int* __restrict__ listIdx)
{
    int i = blockIdx.x * 256 + threadIdx.x;
    listVal[i] = -1.0f;
    listIdx[i] = -1;
}

// ---------------------------------------------------------------- K2P v2
// Pair-block GEMM+score, software-pipelined double-buffered staging,
// fully-unrolled inner loop (immediate ds offsets), one tanh per pair.
// All value chains bit-identical to verified R19 k2p (see proofs in text).
__global__ __launch_bounds__(512, 4) void k2p_pairscore(
    const float* __restrict__ Wt, const float* __restrict__ noise,
    float* __restrict__ Sc)
{
    __shared__ __align__(16) float smem[2 * BUFSZ];   // 69 KB
    int bx = blockIdx.x, by = blockIdx.y;
    if (bx < by) return;
    int R = by * 128, C = bx * 128;
    int t = threadIdx.x;
    int ty = t >> 5, tx = t & 31;        // micro 8x4 over 128x128
    int kf = ty;                          // staging k-row 0..15
    int rr = tx * 4;
    int rrs = rr + ((rr >> 5) << 2);      // swizzled Y write col
    int boff = tx * 4 + ((tx >> 3) << 2); // swizzled Y read base

    // stage s: X rows xb[s] @R, Y rows yb[s] @C;  s<2 -> A1, else A2
    const int xb[4] = {0, 32, 64, 96};
    const int yb[4] = {64, 96, 0, 32};

    float4 xv0, xv1, yv0, yv1;
#define LOADS(s)                                                              \
    xv0 = *(const float4*)&Wt[(size_t)(xb[s] + kf)      * NN + R + rr];       \
    xv1 = *(const float4*)&Wt[(size_t)(xb[s] + kf + 16) * NN + R + rr];       \
    yv0 = *(const float4*)&Wt[(size_t)(yb[s] + kf)      * NN + C + rr];       \
    yv1 = *(const float4*)&Wt[(size_t)(yb[s] + kf + 16) * NN + C + rr];
#define STORES(b) {                                                           \
    float* sX = smem + (b) * BUFSZ;                                           \
    float* sY = sX + 32 * 132;                                                \
    *(float4*)&sX[kf * 132 + rr]        = xv0;                                \
    *(float4*)&sX[(kf + 16) * 132 + rr] = xv1;                                \
    *(float4*)&sY[kf * 144 + rrs]        = yv0;                               \
    *(float4*)&sY[(kf + 16) * 144 + rrs] = yv1; }

    float A1[8][4], A2[8][4];
#pragma unroll
    for (int i = 0; i < 8; ++i)
#pragma unroll
        for (int j = 0; j < 4; ++j) { A1[i][j] = 0.0f; A2[i][j] = 0.0f; }

    auto COMPUTE = [&](int b, float (&A)[8][4]) {
        const float* sX = smem + b * BUFSZ;
        const float* sY = sX + 32 * 132;
#pragma unroll
        for (int kk = 0; kk < 32; ++kk) {
            float4 a0 = *(const float4*)&sX[kk * 132 + ty * 8];
            float4 a1 = *(const float4*)&sX[kk * 132 + ty * 8 + 4];
            float4 bv = *(const float4*)&sY[kk * 144 + boff];
            float a[8] = {a0.x, a0.y, a0.z, a0.w, a1.x, a1.y, a1.z, a1.w};
            float b4[4] = {bv.x, bv.y, bv.z, bv.w};
#pragma unroll
            for (int i = 0; i < 8; ++i)
#pragma unroll
                for (int j = 0; j < 4; ++j)
                    A[i][j] = fmaf(a[i], b4[j], A[i][j]);
        }
    };

    LOADS(0); STORES(0);
    __syncthreads();
    LOADS(1); COMPUTE(0, A1); STORES(1);
    __syncthreads();
    LOADS(2); COMPUTE(1, A1); STORES(0);
    __syncthreads();
    LOADS(3); COMPUTE(0, A2); STORES(1);
    __syncthreads();
    COMPUTE(1, A2);
#undef LOADS
#undef STORES

    // Epilogue: d = guard(A1-A2); one tanh per pair (odd-exactness proof in
    // header). out1 score = adj1 + m; A1 <- adj2 for the transposed tile.
#pragma unroll
    for (int i = 0; i < 8; ++i) {
        int grow = R + ty * 8 + i;
        float4 nz = *(const float4*)&noise[(size_t)grow * NN + C + tx * 4];
        float4 o;
#pragma unroll
        for (int j = 0; j < 4; ++j) {
            float d  = guard(A1[i][j] - A2[i][j]);
            float ta = xla_tanhf(3.0f * fabsf(d));
            float adj1 = (d > 0.0f) ? ta : 0.0f;
            float adj2 = (d < 0.0f) ? ta : 0.0f;
            float m = guard(0.01f * ((const float*)&nz)[j]);
            ((float*)&o)[j] = adj1 + m;
            A1[i][j] = adj2;
        }
        *(float4*)&Sc[(size_t)grow * NN + C + tx * 4] = o;
    }

    // out2 tile (C,R): score = adj2 + fl(0.01*nz), via 4 transposed slices.
    float* dT = smem;   // aliases buf0 (stage-3 compute used buf1)
#pragma unroll
    for (int s = 0; s < 4; ++s) {
        __syncthreads();
        if ((ty >> 2) == s) {
            int base = ty * 8 - 32 * s;
#pragma unroll
            for (int i = 0; i < 8; ++i)
#pragma unroll
                for (int j = 0; j < 4; ++j)
                    dT[(tx * 4 + j) * 33 + base + i] = A1[i][j];
        }
        __syncthreads();
        int J  = t >> 2;
        int Il = (t & 3) * 8;
        int grow = C + J;
        int gcol = R + 32 * s + Il;
        float4 nz0 = *(const float4*)&noise[(size_t)grow * NN + gcol];
        float4 nz1 = *(const float4*)&noise[(size_t)grow * NN + gcol + 4];
        float4 o0, o1;
        o0.x = dT[J * 33 + Il + 0] + guard(0.01f * nz0.x);
        o0.y = dT[J * 33 + Il + 1] + guard(0.01f * nz0.y);
        o0.z = dT[J * 33 + Il + 2] + guard(0.01f * nz0.z);
        o0.w = dT[J * 33 + Il + 3] + guard(0.01f * nz0.w);
        o1.x = dT[J * 33 + Il + 4] + guard(0.01f * nz1.x);
        o1.y = dT[J * 33 + Il + 5] + guard(0.01f * nz1.y);
        o1.z = dT[J * 33 + Il + 6] + guard(0.01f * nz1.z);
        o1.w = dT[J * 33 + Il + 7] + guard(0.01f * nz1.w);
        *(float4*)&Sc[(size_t)grow * NN + gcol]     = o0;
        *(float4*)&Sc[(size_t)grow * NN + gcol + 4] = o1;
    }
}

// ---------------------------------------------------------------- K3 (VERIFIED)
__global__ __launch_bounds__(256) void k3_screen(
    const float* __restrict__ Sc,
    float* __restrict__ listVal, int* __restrict__ listIdx)
{
    int lane = threadIdx.x & 63;
    int w    = threadIdx.x >> 6;
    int row  = blockIdx.x * 4 + w;
    const float* Srow = Sc + (size_t)row * NN;

    float Lv = listVal[row * 64 + lane];
    int   Lj = listIdx[row * 64 + lane];

    for (int c0 = 0; c0 < NN; c0 += 256) {
        float s0 = Srow[c0 + lane];
        float s1 = Srow[c0 + 64 + lane];
        float s2 = Srow[c0 + 128 + lane];
        float s3 = Srow[c0 + 192 + lane];
#pragma unroll
        for (int u = 0; u < 4; ++u) {
            float s = (u == 0) ? s0 : (u == 1) ? s1 : (u == 2) ? s2 : s3;
            int jb = c0 + u * 64;
            float tau = __shfl(Lv, 63);
            unsigned long long m = __ballot(s > tau);
            while (m) {
                int b = __ffsll((unsigned long long)m) - 1;
                m &= m - 1;
                float v = __shfl(s, b);
                tau = __shfl(Lv, 63);
                if (v > tau) {
                    float Lu = __shfl_up(Lv, 1);
                    int   Ju = __shfl_up(Lj, 1);
                    bool ge  = (Lv >= v);
                    bool geu = (lane == 0) || (Lu >= v);
                    float nv = ge ? Lv : (geu ? v : Lu);
                    int   nj = ge ? Lj : (geu ? (jb + b) : Ju);
                    Lv = nv; Lj = nj;
                }
            }
        }
    }
    listVal[row * 64 + lane] = Lv;
    listIdx[row * 64 + lane] = Lj;
}

// ---------------------------------------------------------------- K4a (VERIFIED)
__global__ __launch_bounds__(256) void k4a_fill(float* __restrict__ out)
{
    int i4 = blockIdx.x * 256 + threadIdx.x;
    int f0 = i4 * 4;
    int row = f0 >> 13;
    int colbase = f0 & 8191;
    int drel = row - colbase;
    float4 z = make_float4(0.f, 0.f, 0.f, 0.f);
    if (drel >= 0 && drel < 4) ((float*)&z)[drel] = 1.0f;
    *(float4*)&out[f0] = z;
}

// ---------------------------------------------------------------- K4b (VERIFIED)
__global__ __launch_bounds__(256) void k4b_scatter(
    const int* __restrict__ listIdx, const float* __restrict__ listVal,
    const float* __restrict__ noise, const int* __restrict__ kptr,
    float* __restrict__ out)
{
    int lane = threadIdx.x & 63;
    int w    = threadIdx.x >> 6;
    int row  = blockIdx.x * 4 + w;
    int kk = kptr[0]; if (kk > 64) kk = 64; if (kk < 1) kk = 1;
    if (lane < kk) {
        int   j = listIdx[row * 64 + lane] & 8191;
        float s = listVal[row * 64 + lane];
        float nz = noise[(size_t)row * NN + j];
        float m = guard(0.01f * nz);
        float adj = s - m;
        if (j == row) adj += 1.0f;
        out[(size_t)row * NN + j] = adj;
    }
}

extern "C" void kernel_launch(void* const* d_in, const int* in_sizes, int n_in,
                              void* d_out, int out_size, void* d_ws, size_t ws_size,
                              hipStream_t stream) {
    (void)in_sizes; (void)n_in; (void)out_size; (void)ws_size;
    const int*   idx   = (const int*)d_in[0];
    const float* emb1  = (const float*)d_in[1];
    const float* emb2  = (const float*)d_in[2];
    const float* w1    = (const float*)d_in[3];
    const float* b1    = (const float*)d_in[4];
    const float* w2    = (const float*)d_in[5];
    const float* b2    = (const float*)d_in[6];
    const float* noise = (const float*)d_in[7];
    const int*   kptr  = (const int*)d_in[8];

    float* out = (float*)d_out;
    float* Sc  = out;                          // score matrix (transient)

    char*  ws      = (char*)d_ws;              // ws >= 9MB proven (R17)
    float* Wt      = (float*)ws;                               // 4 MB
    float* listVal = (float*)(ws + (size_t)4 * 1024 * 1024);   // 2 MB
    int*   listIdx = (int*)  (ws + (size_t)6 * 1024 * 1024);   // 2 MB

    k1_nodevec<<<NN / 4, 256, 0, stream>>>(idx, emb1, emb2, w1, b1, w2, b2, Wt);
    k_init<<<NN * 64 / 256, 256, 0, stream>>>(listVal, listIdx);

    dim3 gp(64, 64);
    k2p_pairscore<<<gp, 512, 0, stream>>>(Wt, noise, Sc);

    k3_screen<<<NN / 4, 256, 0, stream>>>(Sc, listVal, listIdx);

    k4a_fill<<<65536, 256, 0, stream>>>(out);
    k4b_scatter<<<NN / 4, 256, 0, stream>>>(listIdx, listVal, noise, kptr, out);
}

// Round 21
// 485.383 us; speedup vs baseline: 5.1169x; 5.1169x over previous
//
#include <hip/hip_runtime.h>

#define NN 8192
#define DD 64
#define CC 128
#define XCLAMP 7.99881172180175781f

// Optimization barrier: blocks FMA contraction (verified necessary).
__device__ __forceinline__ float guard(float v) {
    asm volatile("" : "+v"(v));
    return v;
}

// ---- EXACT replica of XLA EmitFastTanh f32, with_fma = true (VERIFIED) ----
// Odd bit-exactly (clamp symmetric, p = xc*even(x2), q even, IEEE div) --
// empirically confirmed by R20's absmax 0.0 with the one-tanh epilogue.
__device__ __forceinline__ float xla_tanhf(float x) {
    float xc = fminf(fmaxf(x, -XCLAMP), XCLAMP);
    float x2 = xc * xc;
    float p = fmaf(x2, -2.76076847742355e-16f, 2.00018790482477e-13f);
    p = fmaf(x2, p, -8.60467152213735e-11f);
    p = fmaf(x2, p, 5.12229709037114e-08f);
    p = fmaf(x2, p, 1.48572235717979e-05f);
    p = fmaf(x2, p, 6.37261928875436e-04f);
    p = fmaf(x2, p, 4.89352455891786e-03f);
    p = xc * p;
    float q = fmaf(x2, 1.19825839466702e-06f, 1.18534705686654e-04f);
    q = fmaf(x2, q, 2.26843463243900e-03f);
    q = fmaf(x2, q, 4.89352518554385e-03f);
    float r = p / q;
    return (fabsf(x) < 0.0004f) ? x : r;
}

// score = fl(max(tanh(fl(3a)),0) + fl(0.01*nz)), no contraction (VERIFIED)
__device__ __forceinline__ float score_of(float a, float nz) {
    float adj = fmaxf(xla_tanhf(3.0f * a), 0.0f);
    float m = guard(0.01f * nz);
    return adj + m;
}

// ---------------------------------------------------------------- K1 (VERIFIED)
// Nodevecs TRANSPOSED: Wt[c][n], rows 0-63 = nv1 dims, 64-127 = nv2 dims.
__global__ __launch_bounds__(256) void k1_nodevec(
    const int* __restrict__ idx,
    const float* __restrict__ emb1, const float* __restrict__ emb2,
    const float* __restrict__ w1, const float* __restrict__ b1,
    const float* __restrict__ w2, const float* __restrict__ b2,
    float* __restrict__ Wt)
{
    __shared__ float sw1[64 * 65], sw2[64 * 65];
    __shared__ float sb1[64], sb2[64];
    __shared__ float se1[4][64], se2[4][64];
    int t = threadIdx.x;
    for (int i = t; i < 4096; i += 256) {
        int r = i >> 6, c = i & 63;
        sw1[r * 65 + c] = w1[i];
        sw2[r * 65 + c] = w2[i];
    }
    if (t < 64) { sb1[t] = b1[t]; sb2[t] = b2[t]; }
    int nl = t >> 6, d = t & 63;
    int n = blockIdx.x * 4 + nl;
    bool is64 = (idx[1] == 0);
    int g = (is64 ? idx[2 * n] : idx[n]) & 8191;
    se1[nl][d] = emb1[g * 64 + d];
    se2[nl][d] = emb2[g * 64 + d];
    __syncthreads();
    float z1 = 0.0f, z2 = 0.0f;
#pragma unroll 16
    for (int q = 0; q < 64; ++q) {
        z1 = fmaf(se1[nl][q], sw1[d * 65 + q], z1);
        z2 = fmaf(se2[nl][q], sw2[d * 65 + q], z2);
    }
    z1 = 3.0f * guard(z1 + sb1[d]);
    z2 = 3.0f * guard(z2 + sb2[d]);
    Wt[(size_t)d * NN + n]        = xla_tanhf(z1);
    Wt[(size_t)(64 + d) * NN + n] = xla_tanhf(z2);
}

// ---------------------------------------------------------------- K_INIT
__global__ __launch_bounds__(256) void k_init(
    float* __restrict__ listVal, int* __restrict__ listIdx)
{
    int i = blockIdx.x * 256 + threadIdx.x;
    listVal[i] = -1.0f;
    listIdx[i] = -1;
}

// ---------------------------------------------------------------- K2P (R18 + verified one-tanh epilogue)
// Pair-block GEMM+score. Exactly R18's staging/GEMM (VGPR 60, no spill);
// epilogue computes ONE tanh per antisymmetric pair (R20-verified bit-exact):
// ta = tanh(3|d|); adj1 = d>0?ta:0 (== max(tanh(3d),0));
// adj2 = d<0?ta:0 (== max(tanh(-3d),0)). dT carries adj2.
__global__ __launch_bounds__(512) void k2p_pairscore(
    const float* __restrict__ Wt, const float* __restrict__ noise,
    float* __restrict__ Sc)
{
    __shared__ __align__(16) float smem[17024];   // 4x(32x132) staging; 128x133 dT
    float* sA1 = smem;              // nv1[R] k-major
    float* sB1 = smem + 4224;       // nv2[C]
    float* sA2 = smem + 8448;       // nv2[R]
    float* sB2 = smem + 12672;      // nv1[C]
    int bx = blockIdx.x, by = blockIdx.y;
    if (bx < by) return;
    int R = by * 128, C = bx * 128;
    int t = threadIdx.x;
    int ty = t >> 5, tx = t & 31;   // 16 x 32 -> micro 8x4

    float A1[8][4], A2[8][4];
#pragma unroll
    for (int i = 0; i < 8; ++i)
#pragma unroll
        for (int j = 0; j < 4; ++j) { A1[i][j] = 0.0f; A2[i][j] = 0.0f; }

    for (int kc = 0; kc < 2; ++kc) {
        int k0 = kc * 32;
#pragma unroll
        for (int p = 0; p < 2; ++p) {
            int q = p * 512 + t;            // 0..1023
            int kf = q >> 5;                // 0..31
            int rr = (q & 31) * 4;          // 0..124
            float4 v1 = *(const float4*)&Wt[(size_t)(k0 + kf) * NN + R + rr];
            *(float4*)&sA1[kf * 132 + rr] = v1;
            float4 v2 = *(const float4*)&Wt[(size_t)(64 + k0 + kf) * NN + C + rr];
            *(float4*)&sB1[kf * 132 + rr] = v2;
            float4 v3 = *(const float4*)&Wt[(size_t)(64 + k0 + kf) * NN + R + rr];
            *(float4*)&sA2[kf * 132 + rr] = v3;
            float4 v4 = *(const float4*)&Wt[(size_t)(k0 + kf) * NN + C + rr];
            *(float4*)&sB2[kf * 132 + rr] = v4;
        }
        __syncthreads();
#pragma unroll 4
        for (int kk = 0; kk < 32; ++kk) {
            float4 a10 = *(const float4*)&sA1[kk * 132 + ty * 8];
            float4 a11 = *(const float4*)&sA1[kk * 132 + ty * 8 + 4];
            float4 b1v = *(const float4*)&sB1[kk * 132 + tx * 4];
            float4 a20 = *(const float4*)&sA2[kk * 132 + ty * 8];
            float4 a21 = *(const float4*)&sA2[kk * 132 + ty * 8 + 4];
            float4 b2v = *(const float4*)&sB2[kk * 132 + tx * 4];
            float a1[8] = {a10.x, a10.y, a10.z, a10.w, a11.x, a11.y, a11.z, a11.w};
            float b1[4] = {b1v.x, b1v.y, b1v.z, b1v.w};
            float a2[8] = {a20.x, a20.y, a20.z, a20.w, a21.x, a21.y, a21.z, a21.w};
            float b2[4] = {b2v.x, b2v.y, b2v.z, b2v.w};
#pragma unroll
            for (int i = 0; i < 8; ++i)
#pragma unroll
                for (int j = 0; j < 4; ++j) {
                    A1[i][j] = fmaf(a1[i], b1[j], A1[i][j]);
                    A2[i][j] = fmaf(a2[i], b2[j], A2[i][j]);
                }
        }
        __syncthreads();
    }

    // out1 tile (R,C): one tanh per pair; stash adj2 transposed into LDS.
    float* dT = smem;   // 128 x 133 (aliases dead staging buffers)
#pragma unroll
    for (int i = 0; i < 8; ++i) {
        int I = ty * 8 + i;
        int grow = R + I;
        float4 nz = *(const float4*)&noise[(size_t)grow * NN + C + tx * 4];
        float4 o;
#pragma unroll
        for (int j = 0; j < 4; ++j) {
            float d  = guard(A1[i][j] - A2[i][j]);
            float ta = xla_tanhf(3.0f * fabsf(d));
            float adj1 = (d > 0.0f) ? ta : 0.0f;
            float adj2 = (d < 0.0f) ? ta : 0.0f;
            float m = guard(0.01f * ((const float*)&nz)[j]);
            ((float*)&o)[j] = adj1 + m;
            dT[(tx * 4 + j) * 133 + I] = adj2;
        }
        *(float4*)&Sc[(size_t)grow * NN + C + tx * 4] = o;
    }
    __syncthreads();

    // out2 tile (C,R): score = adj2 + fl(0.01*nz), coalesced.
    int c4 = tx * 4;
#pragma unroll
    for (int rr = 0; rr < 8; ++rr) {
        int r2 = rr * 16 + ty;              // 0..127
        int grow = C + r2;
        float4 nz = *(const float4*)&noise[(size_t)grow * NN + R + c4];
        float4 o;
        o.x = dT[r2 * 133 + c4 + 0] + guard(0.01f * nz.x);
        o.y = dT[r2 * 133 + c4 + 1] + guard(0.01f * nz.y);
        o.z = dT[r2 * 133 + c4 + 2] + guard(0.01f * nz.z);
        o.w = dT[r2 * 133 + c4 + 3] + guard(0.01f * nz.w);
        *(float4*)&Sc[(size_t)grow * NN + R + c4] = o;
    }
}

// ---------------------------------------------------------------- K3 (VERIFIED)
__global__ __launch_bounds__(256) void k3_screen(
    const float* __restrict__ Sc,
    float* __restrict__ listVal, int* __restrict__ listIdx)
{
    int lane = threadIdx.x & 63;
    int w    = threadIdx.x >> 6;
    int row  = blockIdx.x * 4 + w;
    const float* Srow = Sc + (size_t)row * NN;

    float Lv = listVal[row * 64 + lane];
    int   Lj = listIdx[row * 64 + lane];

    for (int c0 = 0; c0 < NN; c0 += 256) {
        float s0 = Srow[c0 + lane];
        float s1 = Srow[c0 + 64 + lane];
        float s2 = Srow[c0 + 128 + lane];
        float s3 = Srow[c0 + 192 + lane];
#pragma unroll
        for (int u = 0; u < 4; ++u) {
            float s = (u == 0) ? s0 : (u == 1) ? s1 : (u == 2) ? s2 : s3;
            int jb = c0 + u * 64;
            float tau = __shfl(Lv, 63);
            unsigned long long m = __ballot(s > tau);
            while (m) {
                int b = __ffsll((unsigned long long)m) - 1;
                m &= m - 1;
                float v = __shfl(s, b);
                tau = __shfl(Lv, 63);
                if (v > tau) {
                    float Lu = __shfl_up(Lv, 1);
                    int   Ju = __shfl_up(Lj, 1);
                    bool ge  = (Lv >= v);
                    bool geu = (lane == 0) || (Lu >= v);
                    float nv = ge ? Lv : (geu ? v : Lu);
                    int   nj = ge ? Lj : (geu ? (jb + b) : Ju);
                    Lv = nv; Lj = nj;
                }
            }
        }
    }
    listVal[row * 64 + lane] = Lv;
    listIdx[row * 64 + lane] = Lj;
}

// ---------------------------------------------------------------- K4a (VERIFIED)
__global__ __launch_bounds__(256) void k4a_fill(float* __restrict__ out)
{
    int i4 = blockIdx.x * 256 + threadIdx.x;
    int f0 = i4 * 4;
    int row = f0 >> 13;
    int colbase = f0 & 8191;
    int drel = row - colbase;
    float4 z = make_float4(0.f, 0.f, 0.f, 0.f);
    if (drel >= 0 && drel < 4) ((float*)&z)[drel] = 1.0f;
    *(float4*)&out[f0] = z;
}

// ---------------------------------------------------------------- K4b (VERIFIED)
__global__ __launch_bounds__(256) void k4b_scatter(
    const int* __restrict__ listIdx, const float* __restrict__ listVal,
    const float* __restrict__ noise, const int* __restrict__ kptr,
    float* __restrict__ out)
{
    int lane = threadIdx.x & 63;
    int w    = threadIdx.x >> 6;
    int row  = blockIdx.x * 4 + w;
    int kk = kptr[0]; if (kk > 64) kk = 64; if (kk < 1) kk = 1;
    if (lane < kk) {
        int   j = listIdx[row * 64 + lane] & 8191;
        float s = listVal[row * 64 + lane];
        float nz = noise[(size_t)row * NN + j];
        float m = guard(0.01f * nz);
        float adj = s - m;
        if (j == row) adj += 1.0f;
        out[(size_t)row * NN + j] = adj;
    }
}

extern "C" void kernel_launch(void* const* d_in, const int* in_sizes, int n_in,
                              void* d_out, int out_size, void* d_ws, size_t ws_size,
                              hipStream_t stream) {
    (void)in_sizes; (void)n_in; (void)out_size; (void)ws_size;
    const int*   idx   = (const int*)d_in[0];
    const float* emb1  = (const float*)d_in[1];
    const float* emb2  = (const float*)d_in[2];
    const float* w1    = (const float*)d_in[3];
    const float* b1    = (const float*)d_in[4];
    const float* w2    = (const float*)d_in[5];
    const float* b2    = (const float*)d_in[6];
    const float* noise = (const float*)d_in[7];
    const int*   kptr  = (const int*)d_in[8];

    float* out = (float*)d_out;
    float* Sc  = out;                          // score matrix (transient)

    char*  ws      = (char*)d_ws;              // ws >= 9MB proven (R17)
    float* Wt      = (float*)ws;                               // 4 MB
    float* listVal = (float*)(ws + (size_t)4 * 1024 * 1024);   // 2 MB
    int*   listIdx = (int*)  (ws + (size_t)6 * 1024 * 1024);   // 2 MB

    k1_nodevec<<<NN / 4, 256, 0, stream>>>(idx, emb1, emb2, w1, b1, w2, b2, Wt);
    k_init<<<NN * 64 / 256, 256, 0, stream>>>(listVal, listIdx);

    dim3 gp(64, 64);
    k2p_pairscore<<<gp, 512, 0, stream>>>(Wt, noise, Sc);

    k3_screen<<<NN / 4, 256, 0, stream>>>(Sc, listVal, listIdx);

    k4a_fill<<<65536, 256, 0, stream>>>(out);
    k4b_scatter<<<NN / 4, 256, 0, stream>>>(listIdx, listVal, noise, kptr, out);
}